// Round 5
// baseline (2737.875 us; speedup 1.0000x reference)
//
#include <hip/hip_runtime.h>
#include <math.h>

namespace {

constexpr int kC = 512;
constexpr int kH = 512;
constexpr int kN = 64;
constexpr int kMat = kC * kH;                    // 262144
constexpr float kInvS = 0.04419417382415922f;    // 1/sqrt(512)

enum { SRC_RAW = 0, SRC_X, SRC_T2, SRC_T3, SRC_T4, SRC_T5, SRC_T7, SRC_T11 };

using bf16x8 = __attribute__((ext_vector_type(8))) __bf16;
using f32x4  = __attribute__((ext_vector_type(4))) float;

__device__ __forceinline__ float4 ld4(const float* p) {
  return *reinterpret_cast<const float4*>(p);
}

// elem4<SRC>: elements [r][s..s+3] of the chosen (virtual) tensor.
// For derived tensors r is the c-index, s is the h-index.
template <int SRC>
__device__ __forceinline__ float4 elem4(const float* __restrict__ raw,
                                        const float* __restrict__ x,
                                        const float* __restrict__ t1,
                                        const float* __restrict__ p7,
                                        int n, int r, int s) {
  const int nb = n * kMat;
  if constexpr (SRC == SRC_RAW) {
    return ld4(raw + nb + r * kH + s);
  } else if constexpr (SRC == SRC_X) {
    return ld4(x + nb + r * kH + s);
  } else if constexpr (SRC == SRC_T5) {
    float4 v = ld4(x + nb + r * kH + s);
    return make_float4(fmaxf(v.x, 0.f), fmaxf(v.y, 0.f),
                       fmaxf(v.z, 0.f), fmaxf(v.w, 0.f));
  } else if constexpr (SRC == SRC_T7) {
    float4 v = ld4(x + nb + r * kH + s);
    float4 p = ld4(p7 + r * kH + s);
    return make_float4(p.x * fmaxf(v.x, 0.f), p.y * fmaxf(v.y, 0.f),
                       p.z * fmaxf(v.z, 0.f), p.w * fmaxf(v.w, 0.f));
  } else {
    const int rr = (r + kC - 2) & (kC - 1);      // rolled c-index
    float4 xr = ld4(x + nb + rr * kH + s);
    if constexpr (SRC == SRC_T2) return xr;
    float4 tv = ld4(t1 + n * kH + s);
    float4 t3 = make_float4(tv.x + xr.x, tv.y + xr.y, tv.z + xr.z, tv.w + xr.w);
    if constexpr (SRC == SRC_T3) return t3;
    float4 xv = ld4(x + nb + r * kH + s);
    float4 t4 = make_float4(xv.x * t3.x, xv.y * t3.y, xv.z * t3.z, xv.w * t3.w);
    if constexpr (SRC == SRC_T4) return t4;
    return make_float4(fminf(t4.x, xv.x), fminf(t4.y, xv.y),
                       fminf(t4.z, xv.z), fminf(t4.w, xv.w));  // T11
  }
}

// packed f32 pair -> bf16 pair (hw round)
__device__ __forceinline__ unsigned cvtpk(float lo, float hi) {
  unsigned r;
  asm("v_cvt_pk_bf16_f32 %0, %1, %2" : "=v"(r) : "v"(lo), "v"(hi));
  return r;
}

// exact 3-plane split of two f32 values (pair along K)
__device__ __forceinline__ void split2(float a, float b, unsigned& q0,
                                       unsigned& q1, unsigned& q2) {
  q0 = cvtpk(a, b);
  float a0 = __builtin_bit_cast(float, q0 << 16);
  float b0 = __builtin_bit_cast(float, q0 & 0xFFFF0000u);
  float ra = a - a0, rb = b - b0;
  q1 = cvtpk(ra, rb);
  float a1 = __builtin_bit_cast(float, q1 << 16);
  float b1 = __builtin_bit_cast(float, q1 & 0xFFFF0000u);
  q2 = cvtpk(ra - a1, rb - b1);
}

// ---- LDS geometry (ushort units) --------------------------------------
// Plane = 128 rows x 32 ushorts, 2 rows per 128B line. 16B slot
// s = ((r&1)<<2)|(ku>>3) XOR-swizzled with line index -> fragment reads
// land 2-way per bank (free, m136) instead of 8-way.
constexpr int kPlane = 128 * 32;                 // 4096 ushorts = 8 KiB
constexpr int kMatS = 3 * kPlane;                // per-matrix (3 planes)

__device__ __forceinline__ int lds_addr(int r, int ku) {
  int line = r >> 1;
  int slot = ((r & 1) << 2) | (ku >> 3);
  return (line << 6) + ((slot ^ (line & 7)) << 3) + (ku & 7);
}

__device__ __forceinline__ void store3(unsigned short* dst, int r, int ku,
                                       unsigned p0a, unsigned p0b,
                                       unsigned p1a, unsigned p1b,
                                       unsigned p2a, unsigned p2b) {
  int off = lds_addr(r, ku);
  *reinterpret_cast<uint2*>(dst + off)              = make_uint2(p0a, p0b);
  *reinterpret_cast<uint2*>(dst + kPlane + off)     = make_uint2(p1a, p1b);
  *reinterpret_cast<uint2*>(dst + 2 * kPlane + off) = make_uint2(p2a, p2b);
}

// ---- staging, split into LOAD (global->reg, vectorized) and WRITE
// (split+ds_write), so loads for tile k+1 can be issued while MFMA of
// tile k runs (T14 async-STAGE split).
// Register tile layout v[4][4]:
//   TRANS=0: unit u: e=tid+u*256, row=e>>3, ku=(e&7)*4; v[u][j] = elem j.
//   TRANS=1: kb=tid>>5, mb=tid&31; v[j][i] = elem(k=k0+4kb+j, row=4mb+i).
template <int SRC, bool TRANS>
__device__ __forceinline__ void stage_load(float v[4][4],
                                           const float* __restrict__ raw,
                                           const float* __restrict__ x,
                                           const float* __restrict__ t1,
                                           const float* __restrict__ p7,
                                           int n, int r0, int k0, int tid) {
  if constexpr (!TRANS) {
#pragma unroll
    for (int u = 0; u < 4; ++u) {
      int e = tid + u * 256;
      float4 t = elem4<SRC>(raw, x, t1, p7, n, r0 + (e >> 3),
                            k0 + ((e & 7) << 2));
      v[u][0] = t.x; v[u][1] = t.y; v[u][2] = t.z; v[u][3] = t.w;
    }
  } else {
    int kb = tid >> 5, mb = tid & 31;
#pragma unroll
    for (int j = 0; j < 4; ++j) {
      float4 t = elem4<SRC>(raw, x, t1, p7, n, k0 + kb * 4 + j, r0 + mb * 4);
      v[j][0] = t.x; v[j][1] = t.y; v[j][2] = t.z; v[j][3] = t.w;
    }
  }
}

template <bool TRANS>
__device__ __forceinline__ void stage_write(unsigned short* dst,
                                            const float v[4][4], int tid) {
  if constexpr (!TRANS) {
#pragma unroll
    for (int u = 0; u < 4; ++u) {
      int e = tid + u * 256;
      unsigned p0a, p1a, p2a, p0b, p1b, p2b;
      split2(v[u][0], v[u][1], p0a, p1a, p2a);
      split2(v[u][2], v[u][3], p0b, p1b, p2b);
      store3(dst, e >> 3, (e & 7) << 2, p0a, p0b, p1a, p1b, p2a, p2b);
    }
  } else {
    int kb = tid >> 5, mb = tid & 31;
#pragma unroll
    for (int i = 0; i < 4; ++i) {                // 4x4 in-register transpose
      unsigned q0a, q1a, q2a, q0b, q1b, q2b;
      split2(v[0][i], v[1][i], q0a, q1a, q2a);
      split2(v[2][i], v[3][i], q0b, q1b, q2b);
      store3(dst, mb * 4 + i, kb * 4, q0a, q0b, q1a, q1b, q2a, q2b);
    }
  }
}

// C[i,j] = alpha * sum_k opA(i,k)*opB(k,j); 512x512 per batch; bf16x3-split
// MFMA (6 products) with f32 accumulate; async reg-prefetch k-loop.
template <int ASRC, int AT, int BSRC, int BT>
__global__ __launch_bounds__(256, 3) void gemm_kernel(
    const float* __restrict__ Araw, const float* __restrict__ Braw,
    const float* __restrict__ x, const float* __restrict__ t1,
    const float* __restrict__ p7, float* __restrict__ C, float alpha) {
  __shared__ unsigned short smem[2 * kMatS];     // 49152 B -> 3 blocks/CU
  const int n = blockIdx.z;
  const int i0 = blockIdx.y * 128;
  const int j0 = blockIdx.x * 128;
  const int tid = threadIdx.x;
  const int lane = tid & 63;
  const int wid = tid >> 6;
  const int wr = wid >> 1, wc = wid & 1;         // wave -> 64x64 sub-tile

  f32x4 acc[4][4];
#pragma unroll
  for (int a = 0; a < 4; ++a)
#pragma unroll
    for (int b = 0; b < 4; ++b) acc[a][b] = (f32x4)0.f;

  const int frow = lane & 15;                    // fragment row/col within 16
  const int kq = (lane >> 4) * 8;                // k-offset (ushort units)

  float vA[4][4], vB[4][4];
  stage_load<ASRC, AT == 1>(vA, Araw, x, t1, p7, n, i0, 0, tid);
  stage_load<BSRC, BT == 0>(vB, Braw, x, t1, p7, n, j0, 0, tid);

  for (int k0 = 0; k0 < kC; k0 += 32) {
    stage_write<AT == 1>(smem, vA, tid);
    stage_write<BT == 0>(smem + kMatS, vB, tid);
    __syncthreads();
    if (k0 + 32 < kC) {                          // issue loads for next tile;
      stage_load<ASRC, AT == 1>(vA, Araw, x, t1, p7, n, i0, k0 + 32, tid);
      stage_load<BSRC, BT == 0>(vB, Braw, x, t1, p7, n, j0, k0 + 32, tid);
    }                                            // they complete under MFMA

    bf16x8 B0[4], B1[4], B2[4];
#pragma unroll
    for (int nj = 0; nj < 4; ++nj) {
      int off = kMatS + lds_addr(wc * 64 + nj * 16 + frow, kq);
      B0[nj] = *reinterpret_cast<const bf16x8*>(smem + off);
      B1[nj] = *reinterpret_cast<const bf16x8*>(smem + kPlane + off);
      B2[nj] = *reinterpret_cast<const bf16x8*>(smem + 2 * kPlane + off);
    }
#pragma unroll
    for (int mi = 0; mi < 4; ++mi) {
      int off = lds_addr(wr * 64 + mi * 16 + frow, kq);
      bf16x8 A0 = *reinterpret_cast<const bf16x8*>(smem + off);
      bf16x8 A1 = *reinterpret_cast<const bf16x8*>(smem + kPlane + off);
      bf16x8 A2 = *reinterpret_cast<const bf16x8*>(smem + 2 * kPlane + off);
#pragma unroll
      for (int nj = 0; nj < 4; ++nj) {
        f32x4 c = acc[mi][nj];
        c = __builtin_amdgcn_mfma_f32_16x16x32_bf16(A1, B1[nj], c, 0, 0, 0);
        c = __builtin_amdgcn_mfma_f32_16x16x32_bf16(A0, B2[nj], c, 0, 0, 0);
        c = __builtin_amdgcn_mfma_f32_16x16x32_bf16(A2, B0[nj], c, 0, 0, 0);
        c = __builtin_amdgcn_mfma_f32_16x16x32_bf16(A0, B1[nj], c, 0, 0, 0);
        c = __builtin_amdgcn_mfma_f32_16x16x32_bf16(A1, B0[nj], c, 0, 0, 0);
        c = __builtin_amdgcn_mfma_f32_16x16x32_bf16(A0, B0[nj], c, 0, 0, 0);
        acc[mi][nj] = c;
      }
    }
    __syncthreads();
  }

  // epilogue: C/D layout col=lane&15, row=(lane>>4)*4+reg (m89-verified)
  const int nb = n * kMat;
  const int rbase = (lane >> 4) * 4;
#pragma unroll
  for (int mi = 0; mi < 4; ++mi) {
#pragma unroll
    for (int nj = 0; nj < 4; ++nj) {
      int row0 = i0 + wr * 64 + mi * 16 + rbase;
      int col = j0 + wc * 64 + nj * 16 + frow;
      float* cp = C + nb + row0 * kH + col;
#pragma unroll
      for (int r = 0; r < 4; ++r) cp[r * kH] = acc[mi][nj][r] * alpha;
    }
  }
}

// t1[n,h] = sum_c x[n,c,h] * w[c]
__global__ __launch_bounds__(256) void t1_kernel(const float* __restrict__ x,
                                                 const float* __restrict__ w,
                                                 float* __restrict__ t1) {
  int idx = blockIdx.x * 256 + threadIdx.x;      // n*kH + h
  int n = idx >> 9;
  const float* xp = x + n * kMat + (idx & (kH - 1));
  float s = 0.f;
#pragma unroll 8
  for (int c = 0; c < kC; ++c) s = fmaf(xp[c * kH], w[c], s);
  t1[idx] = s;
}

// in-place stable softmax over rows of 512 floats; one block per row
__global__ __launch_bounds__(256) void softmax_kernel(float* __restrict__ buf) {
  __shared__ float red[8];
  float* p = buf + (size_t)blockIdx.x * kH;
  int t = threadIdx.x;
  float2 v = reinterpret_cast<float2*>(p)[t];
  float m = fmaxf(v.x, v.y);
#pragma unroll
  for (int o = 32; o; o >>= 1) m = fmaxf(m, __shfl_xor(m, o));
  if ((t & 63) == 0) red[t >> 6] = m;
  __syncthreads();
  m = fmaxf(fmaxf(red[0], red[1]), fmaxf(red[2], red[3]));
  float e0 = expf(v.x - m), e1 = expf(v.y - m);
  float s = e0 + e1;
#pragma unroll
  for (int o = 32; o; o >>= 1) s += __shfl_xor(s, o);
  __syncthreads();
  if ((t & 63) == 0) red[4 + (t >> 6)] = s;
  __syncthreads();
  s = red[4] + red[5] + red[6] + red[7];
  float inv = 1.f / s;
  reinterpret_cast<float2*>(p)[t] = make_float2(e0 * inv, e1 * inv);
}

}  // namespace

extern "C" void kernel_launch(void* const* d_in, const int* in_sizes, int n_in,
                              void* d_out, int out_size, void* d_ws,
                              size_t ws_size, hipStream_t stream) {
  (void)in_sizes; (void)n_in; (void)out_size;
  const float* x  = (const float*)d_in[0];
  const float* w  = (const float*)d_in[1];   // p1_w (C,1)
  const float* p7 = (const float*)d_in[2];   // p7_w (1,C,H)
  float* out = (float*)d_out;

  const size_t BUF = (size_t)kN * kMat;
  const size_t need = (4 * BUF + (size_t)kN * kH) * sizeof(float);
  float* ws = (float*)d_ws;
  if (ws_size < need) {
    static float* g_extra = nullptr;           // first (uncaptured) call only
    if (!g_extra) (void)hipMalloc((void**)&g_extra, need);
    ws = g_extra;
  }
  float* b0 = ws;
  float* b1 = b0 + BUF;
  float* b2 = b1 + BUF;
  float* b3 = b2 + BUF;
  float* t1 = b3 + BUF;

  dim3 gg(4, 4, kN);
  dim3 bb(256);
  const int rows = kN * kH;                    // 32768

  t1_kernel<<<rows / 256, bb, 0, stream>>>(x, w, t1);

  // t9 = t5 @ t4^T * invS                                  -> b0
  gemm_kernel<SRC_T5, 0, SRC_T4, 1><<<gg, bb, 0, stream>>>(nullptr, nullptr, x, t1, p7, b0, kInvS);
  // t10 = softmax(t7 @ t3^T * invS)                        -> b1
  gemm_kernel<SRC_T7, 0, SRC_T3, 1><<<gg, bb, 0, stream>>>(nullptr, nullptr, x, t1, p7, b1, kInvS);
  softmax_kernel<<<rows, bb, 0, stream>>>(b1);
  // t14 = softmax(S14), S14[i,j] = sum_k t9[k,i]*t10[j,k]  -> b2
  gemm_kernel<SRC_RAW, 1, SRC_RAW, 1><<<gg, bb, 0, stream>>>(b0, b1, x, t1, p7, b2, kInvS);
  softmax_kernel<<<rows, bb, 0, stream>>>(b2);
  // t12[i,h] = sum_d t9[d,i]*t7[d,h] * invS                -> b1 (t10 dead)
  gemm_kernel<SRC_RAW, 1, SRC_T7, 0><<<gg, bb, 0, stream>>>(b0, nullptr, x, t1, p7, b1, kInvS);
  // t16[h,j] = sum_k t12[k,h]*t14[j,k] * invS              -> b0 (t9 dead)
  gemm_kernel<SRC_RAW, 1, SRC_RAW, 1><<<gg, bb, 0, stream>>>(b1, b2, x, t1, p7, b0, kInvS);
  // t13[h,g] = sum_c t11[c,h]*t2[c,g] * invS               -> b1 (t12 dead)
  gemm_kernel<SRC_T11, 1, SRC_T2, 0><<<gg, bb, 0, stream>>>(nullptr, nullptr, x, t1, p7, b1, kInvS);
  // t8 = softmax(t5^T @ x * invS)                          -> b2 (t14 dead)
  gemm_kernel<SRC_T5, 1, SRC_X, 0><<<gg, bb, 0, stream>>>(nullptr, nullptr, x, t1, p7, b2, kInvS);
  softmax_kernel<<<rows, bb, 0, stream>>>(b2);
  // t15 = softmax(t13 @ t8 * invS)                         -> b3
  gemm_kernel<SRC_RAW, 0, SRC_RAW, 0><<<gg, bb, 0, stream>>>(b1, b2, x, t1, p7, b3, kInvS);
  softmax_kernel<<<rows, bb, 0, stream>>>(b3);
  // t17[c,j] = sum_k t16[k,c]*t15[k,j] * invS              -> out
  gemm_kernel<SRC_RAW, 1, SRC_RAW, 0><<<gg, bb, 0, stream>>>(b0, b3, x, t1, p7, out, kInvS);
}

// Round 6
// 1375.708 us; speedup vs baseline: 1.9902x; 1.9902x over previous
//
#include <hip/hip_runtime.h>
#include <math.h>

namespace {

constexpr int kC = 512;
constexpr int kH = 512;
constexpr int kN = 64;
constexpr int kMat = kC * kH;                    // 262144
constexpr float kInvS = 0.04419417382415922f;    // 1/sqrt(512)

enum { SRC_RAW = 0, SRC_X, SRC_T2, SRC_T3, SRC_T4, SRC_T5, SRC_T7, SRC_T11 };

using bf16x8 = __attribute__((ext_vector_type(8))) __bf16;
using f32x4  = __attribute__((ext_vector_type(4))) float;
using f4     = __attribute__((ext_vector_type(4))) float;

__device__ __forceinline__ f4 ld4(const float* p) {
  return *reinterpret_cast<const f4*>(p);
}
__device__ __forceinline__ f4 relu4(f4 v) {
  return (f4){fmaxf(v.x, 0.f), fmaxf(v.y, 0.f), fmaxf(v.z, 0.f),
              fmaxf(v.w, 0.f)};
}
__device__ __forceinline__ f4 min4(f4 a, f4 b) {
  return (f4){fminf(a.x, b.x), fminf(a.y, b.y), fminf(a.z, b.z),
              fminf(a.w, b.w)};
}

// elem4<SRC>: elements [r][s..s+3] of the chosen (virtual) tensor.
template <int SRC>
__device__ __forceinline__ f4 elem4(const float* __restrict__ raw,
                                    const float* __restrict__ x,
                                    const float* __restrict__ t1,
                                    const float* __restrict__ p7,
                                    int n, int r, int s) {
  const int nb = n * kMat;
  if constexpr (SRC == SRC_RAW) {
    return ld4(raw + nb + r * kH + s);
  } else if constexpr (SRC == SRC_X) {
    return ld4(x + nb + r * kH + s);
  } else if constexpr (SRC == SRC_T5) {
    return relu4(ld4(x + nb + r * kH + s));
  } else if constexpr (SRC == SRC_T7) {
    return ld4(p7 + r * kH + s) * relu4(ld4(x + nb + r * kH + s));
  } else {
    const int rr = (r + kC - 2) & (kC - 1);      // rolled c-index
    f4 xr = ld4(x + nb + rr * kH + s);
    if constexpr (SRC == SRC_T2) return xr;
    f4 t3 = ld4(t1 + n * kH + s) + xr;
    if constexpr (SRC == SRC_T3) return t3;
    f4 xv = ld4(x + nb + r * kH + s);
    f4 t4 = xv * t3;
    if constexpr (SRC == SRC_T4) return t4;
    return min4(t4, xv);                         // T11
  }
}

// packed f32 pair -> bf16 pair (hw round)
__device__ __forceinline__ unsigned cvtpk(float lo, float hi) {
  unsigned r;
  asm("v_cvt_pk_bf16_f32 %0, %1, %2" : "=v"(r) : "v"(lo), "v"(hi));
  return r;
}

// exact 3-plane split of two f32 values (pair along K)
__device__ __forceinline__ void split2(float a, float b, unsigned& q0,
                                       unsigned& q1, unsigned& q2) {
  q0 = cvtpk(a, b);
  float a0 = __builtin_bit_cast(float, q0 << 16);
  float b0 = __builtin_bit_cast(float, q0 & 0xFFFF0000u);
  float ra = a - a0, rb = b - b0;
  q1 = cvtpk(ra, rb);
  float a1 = __builtin_bit_cast(float, q1 << 16);
  float b1 = __builtin_bit_cast(float, q1 & 0xFFFF0000u);
  q2 = cvtpk(ra - a1, rb - b1);
}

// ---- LDS geometry (ushort units) --------------------------------------
// Plane = 128 rows x 32 ushorts, 2 rows per 128B line. 16B slot
// s = ((r&1)<<2)|(ku>>3) XOR-swizzled with line index -> fragment reads
// land 2-way per bank (free, m136) instead of 8-way.
constexpr int kPlane = 128 * 32;                 // 4096 ushorts = 8 KiB
constexpr int kMatS = 3 * kPlane;                // per-matrix (3 planes)

__device__ __forceinline__ int lds_addr(int r, int ku) {
  int line = r >> 1;
  int slot = ((r & 1) << 2) | (ku >> 3);
  return (line << 6) + ((slot ^ (line & 7)) << 3) + (ku & 7);
}

__device__ __forceinline__ void store3(unsigned short* dst, int r, int ku,
                                       unsigned p0a, unsigned p0b,
                                       unsigned p1a, unsigned p1b,
                                       unsigned p2a, unsigned p2b) {
  int off = lds_addr(r, ku);
  *reinterpret_cast<uint2*>(dst + off)              = make_uint2(p0a, p0b);
  *reinterpret_cast<uint2*>(dst + kPlane + off)     = make_uint2(p1a, p1b);
  *reinterpret_cast<uint2*>(dst + 2 * kPlane + off) = make_uint2(p2a, p2b);
}

// ---- staging, split into LOAD (global->reg, vectorized) and WRITE
// (split+ds_write). Prefetch tile is a struct of four named f4 vectors,
// by-value only: no arrays / pointer params, so SROA keeps it in VGPRs
// (R5's float[4][4] variant went to scratch: 3.5 GB WRITE_SIZE).
struct Tile4 { f4 a, b, c, d; };

// TRANS=0: member m in {a,b,c,d} <-> u, e=tid+u*256, row=e>>3, ku=(e&7)*4;
//          member = elem(row, ku..ku+3).
// TRANS=1: kb=tid>>5, mb=tid&31; member j = elem(k=k0+4kb+j, rows 4mb..4mb+3).
template <int SRC, bool TRANS>
__device__ __forceinline__ Tile4 stage_load(const float* __restrict__ raw,
                                            const float* __restrict__ x,
                                            const float* __restrict__ t1,
                                            const float* __restrict__ p7,
                                            int n, int r0, int k0, int tid) {
  Tile4 t;
  if constexpr (!TRANS) {
    t.a = elem4<SRC>(raw, x, t1, p7, n, r0 + (tid >> 3), k0 + ((tid & 7) << 2));
    int e1 = tid + 256;
    t.b = elem4<SRC>(raw, x, t1, p7, n, r0 + (e1 >> 3), k0 + ((e1 & 7) << 2));
    int e2 = tid + 512;
    t.c = elem4<SRC>(raw, x, t1, p7, n, r0 + (e2 >> 3), k0 + ((e2 & 7) << 2));
    int e3 = tid + 768;
    t.d = elem4<SRC>(raw, x, t1, p7, n, r0 + (e3 >> 3), k0 + ((e3 & 7) << 2));
  } else {
    int kb = tid >> 5, mb = tid & 31;
    t.a = elem4<SRC>(raw, x, t1, p7, n, k0 + kb * 4 + 0, r0 + mb * 4);
    t.b = elem4<SRC>(raw, x, t1, p7, n, k0 + kb * 4 + 1, r0 + mb * 4);
    t.c = elem4<SRC>(raw, x, t1, p7, n, k0 + kb * 4 + 2, r0 + mb * 4);
    t.d = elem4<SRC>(raw, x, t1, p7, n, k0 + kb * 4 + 3, r0 + mb * 4);
  }
  return t;
}

template <bool TRANS>
__device__ __forceinline__ void stage_write(unsigned short* dst, Tile4 t,
                                            int tid) {
  if constexpr (!TRANS) {
#define ST_ROW(m, u)                                              \
  {                                                               \
    int e = tid + (u)*256;                                        \
    unsigned p0a, p1a, p2a, p0b, p1b, p2b;                        \
    split2(t.m.x, t.m.y, p0a, p1a, p2a);                          \
    split2(t.m.z, t.m.w, p0b, p1b, p2b);                          \
    store3(dst, e >> 3, (e & 7) << 2, p0a, p0b, p1a, p1b, p2a, p2b); \
  }
    ST_ROW(a, 0) ST_ROW(b, 1) ST_ROW(c, 2) ST_ROW(d, 3)
#undef ST_ROW
  } else {
    int kb = tid >> 5, mb = tid & 31;
#define ST_XP(comp, i)                                            \
  {                                                               \
    unsigned q0a, q1a, q2a, q0b, q1b, q2b;                        \
    split2(t.a.comp, t.b.comp, q0a, q1a, q2a);                    \
    split2(t.c.comp, t.d.comp, q0b, q1b, q2b);                    \
    store3(dst, mb * 4 + (i), kb * 4, q0a, q0b, q1a, q1b, q2a, q2b); \
  }
    ST_XP(x, 0) ST_XP(y, 1) ST_XP(z, 2) ST_XP(w, 3)
#undef ST_XP
  }
}

// C[i,j] = alpha * sum_k opA(i,k)*opB(k,j); 512x512 per batch; bf16x3-split
// MFMA (6 products) with f32 accumulate; reg-prefetch of next k-tile.
template <int ASRC, int AT, int BSRC, int BT>
__global__ __launch_bounds__(256, 3) void gemm_kernel(
    const float* __restrict__ Araw, const float* __restrict__ Braw,
    const float* __restrict__ x, const float* __restrict__ t1,
    const float* __restrict__ p7, float* __restrict__ C, float alpha) {
  __shared__ unsigned short smem[2 * kMatS];     // 49152 B -> 3 blocks/CU
  const int n = blockIdx.z;
  const int i0 = blockIdx.y * 128;
  const int j0 = blockIdx.x * 128;
  const int tid = threadIdx.x;
  const int lane = tid & 63;
  const int wid = tid >> 6;
  const int wr = wid >> 1, wc = wid & 1;         // wave -> 64x64 sub-tile

  f32x4 acc[4][4];
#pragma unroll
  for (int a = 0; a < 4; ++a)
#pragma unroll
    for (int b = 0; b < 4; ++b) acc[a][b] = (f32x4)0.f;

  const int frow = lane & 15;                    // fragment row/col within 16
  const int kq = (lane >> 4) * 8;                // k-offset (ushort units)

  Tile4 vA = stage_load<ASRC, AT == 1>(Araw, x, t1, p7, n, i0, 0, tid);
  Tile4 vB = stage_load<BSRC, BT == 0>(Braw, x, t1, p7, n, j0, 0, tid);

  for (int k0 = 0; k0 < kC; k0 += 32) {
    stage_write<AT == 1>(smem, vA, tid);
    stage_write<BT == 0>(smem + kMatS, vB, tid);
    __syncthreads();
    if (k0 + 32 < kC) {                          // issue next-tile loads; they
      vA = stage_load<ASRC, AT == 1>(Araw, x, t1, p7, n, i0, k0 + 32, tid);
      vB = stage_load<BSRC, BT == 0>(Braw, x, t1, p7, n, j0, k0 + 32, tid);
    }                                            // complete under the MFMAs

    bf16x8 B0[4], B1[4], B2[4];
#pragma unroll
    for (int nj = 0; nj < 4; ++nj) {
      int off = kMatS + lds_addr(wc * 64 + nj * 16 + frow, kq);
      B0[nj] = *reinterpret_cast<const bf16x8*>(smem + off);
      B1[nj] = *reinterpret_cast<const bf16x8*>(smem + kPlane + off);
      B2[nj] = *reinterpret_cast<const bf16x8*>(smem + 2 * kPlane + off);
    }
#pragma unroll
    for (int mi = 0; mi < 4; ++mi) {
      int off = lds_addr(wr * 64 + mi * 16 + frow, kq);
      bf16x8 A0 = *reinterpret_cast<const bf16x8*>(smem + off);
      bf16x8 A1 = *reinterpret_cast<const bf16x8*>(smem + kPlane + off);
      bf16x8 A2 = *reinterpret_cast<const bf16x8*>(smem + 2 * kPlane + off);
#pragma unroll
      for (int nj = 0; nj < 4; ++nj) {
        f32x4 c = acc[mi][nj];
        c = __builtin_amdgcn_mfma_f32_16x16x32_bf16(A1, B1[nj], c, 0, 0, 0);
        c = __builtin_amdgcn_mfma_f32_16x16x32_bf16(A0, B2[nj], c, 0, 0, 0);
        c = __builtin_amdgcn_mfma_f32_16x16x32_bf16(A2, B0[nj], c, 0, 0, 0);
        c = __builtin_amdgcn_mfma_f32_16x16x32_bf16(A0, B1[nj], c, 0, 0, 0);
        c = __builtin_amdgcn_mfma_f32_16x16x32_bf16(A1, B0[nj], c, 0, 0, 0);
        c = __builtin_amdgcn_mfma_f32_16x16x32_bf16(A0, B0[nj], c, 0, 0, 0);
        acc[mi][nj] = c;
      }
    }
    __syncthreads();
  }

  // epilogue: C/D layout col=lane&15, row=(lane>>4)*4+reg (m89-verified)
  const int nb = n * kMat;
  const int rbase = (lane >> 4) * 4;
#pragma unroll
  for (int mi = 0; mi < 4; ++mi) {
#pragma unroll
    for (int nj = 0; nj < 4; ++nj) {
      int row0 = i0 + wr * 64 + mi * 16 + rbase;
      int col = j0 + wc * 64 + nj * 16 + frow;
      float* cp = C + nb + row0 * kH + col;
#pragma unroll
      for (int r = 0; r < 4; ++r) cp[r * kH] = acc[mi][nj][r] * alpha;
    }
  }
}

// t1[n,h] = sum_c x[n,c,h] * w[c]
__global__ __launch_bounds__(256) void t1_kernel(const float* __restrict__ x,
                                                 const float* __restrict__ w,
                                                 float* __restrict__ t1) {
  int idx = blockIdx.x * 256 + threadIdx.x;      // n*kH + h
  int n = idx >> 9;
  const float* xp = x + n * kMat + (idx & (kH - 1));
  float s = 0.f;
#pragma unroll 8
  for (int c = 0; c < kC; ++c) s = fmaf(xp[c * kH], w[c], s);
  t1[idx] = s;
}

// in-place stable softmax over rows of 512 floats; one block per row
__global__ __launch_bounds__(256) void softmax_kernel(float* __restrict__ buf) {
  __shared__ float red[8];
  float* p = buf + (size_t)blockIdx.x * kH;
  int t = threadIdx.x;
  float2 v = reinterpret_cast<float2*>(p)[t];
  float m = fmaxf(v.x, v.y);
#pragma unroll
  for (int o = 32; o; o >>= 1) m = fmaxf(m, __shfl_xor(m, o));
  if ((t & 63) == 0) red[t >> 6] = m;
  __syncthreads();
  m = fmaxf(fmaxf(red[0], red[1]), fmaxf(red[2], red[3]));
  float e0 = expf(v.x - m), e1 = expf(v.y - m);
  float s = e0 + e1;
#pragma unroll
  for (int o = 32; o; o >>= 1) s += __shfl_xor(s, o);
  __syncthreads();
  if ((t & 63) == 0) red[4 + (t >> 6)] = s;
  __syncthreads();
  s = red[4] + red[5] + red[6] + red[7];
  float inv = 1.f / s;
  reinterpret_cast<float2*>(p)[t] = make_float2(e0 * inv, e1 * inv);
}

}  // namespace

extern "C" void kernel_launch(void* const* d_in, const int* in_sizes, int n_in,
                              void* d_out, int out_size, void* d_ws,
                              size_t ws_size, hipStream_t stream) {
  (void)in_sizes; (void)n_in; (void)out_size;
  const float* x  = (const float*)d_in[0];
  const float* w  = (const float*)d_in[1];   // p1_w (C,1)
  const float* p7 = (const float*)d_in[2];   // p7_w (1,C,H)
  float* out = (float*)d_out;

  const size_t BUF = (size_t)kN * kMat;
  const size_t need = (4 * BUF + (size_t)kN * kH) * sizeof(float);
  float* ws = (float*)d_ws;
  if (ws_size < need) {
    static float* g_extra = nullptr;           // first (uncaptured) call only
    if (!g_extra) (void)hipMalloc((void**)&g_extra, need);
    ws = g_extra;
  }
  float* b0 = ws;
  float* b1 = b0 + BUF;
  float* b2 = b1 + BUF;
  float* b3 = b2 + BUF;
  float* t1 = b3 + BUF;

  dim3 gg(4, 4, kN);
  dim3 bb(256);
  const int rows = kN * kH;                    // 32768

  t1_kernel<<<rows / 256, bb, 0, stream>>>(x, w, t1);

  // t9 = t5 @ t4^T * invS                                  -> b0
  gemm_kernel<SRC_T5, 0, SRC_T4, 1><<<gg, bb, 0, stream>>>(nullptr, nullptr, x, t1, p7, b0, kInvS);
  // t10 = softmax(t7 @ t3^T * invS)                        -> b1
  gemm_kernel<SRC_T7, 0, SRC_T3, 1><<<gg, bb, 0, stream>>>(nullptr, nullptr, x, t1, p7, b1, kInvS);
  softmax_kernel<<<rows, bb, 0, stream>>>(b1);
  // t14 = softmax(S14), S14[i,j] = sum_k t9[k,i]*t10[j,k]  -> b2
  gemm_kernel<SRC_RAW, 1, SRC_RAW, 1><<<gg, bb, 0, stream>>>(b0, b1, x, t1, p7, b2, kInvS);
  softmax_kernel<<<rows, bb, 0, stream>>>(b2);
  // t12[i,h] = sum_d t9[d,i]*t7[d,h] * invS                -> b1 (t10 dead)
  gemm_kernel<SRC_RAW, 1, SRC_T7, 0><<<gg, bb, 0, stream>>>(b0, nullptr, x, t1, p7, b1, kInvS);
  // t16[h,j] = sum_k t12[k,h]*t14[j,k] * invS              -> b0 (t9 dead)
  gemm_kernel<SRC_RAW, 1, SRC_RAW, 1><<<gg, bb, 0, stream>>>(b1, b2, x, t1, p7, b0, kInvS);
  // t13[h,g] = sum_c t11[c,h]*t2[c,g] * invS               -> b1 (t12 dead)
  gemm_kernel<SRC_T11, 1, SRC_T2, 0><<<gg, bb, 0, stream>>>(nullptr, nullptr, x, t1, p7, b1, kInvS);
  // t8 = softmax(t5^T @ x * invS)                          -> b2 (t14 dead)
  gemm_kernel<SRC_T5, 1, SRC_X, 0><<<gg, bb, 0, stream>>>(nullptr, nullptr, x, t1, p7, b2, kInvS);
  softmax_kernel<<<rows, bb, 0, stream>>>(b2);
  // t15 = softmax(t13 @ t8 * invS)                         -> b3
  gemm_kernel<SRC_RAW, 0, SRC_RAW, 0><<<gg, bb, 0, stream>>>(b1, b2, x, t1, p7, b3, kInvS);
  softmax_kernel<<<rows, bb, 0, stream>>>(b3);
  // t17[c,j] = sum_k t16[k,c]*t15[k,j] * invS              -> out
  gemm_kernel<SRC_RAW, 1, SRC_RAW, 0><<<gg, bb, 0, stream>>>(b0, b3, x, t1, p7, out, kInvS);
}

// Round 7
// 1366.093 us; speedup vs baseline: 2.0042x; 1.0070x over previous
//
#include <hip/hip_runtime.h>
#include <math.h>

namespace {

constexpr int kC = 512;
constexpr int kH = 512;
constexpr int kN = 64;
constexpr int kMat = kC * kH;                    // 262144
constexpr float kInvS = 0.04419417382415922f;    // 1/sqrt(512)

enum { SRC_RAW = 0, SRC_X, SRC_T2, SRC_T3, SRC_T4, SRC_T5, SRC_T7, SRC_T11 };

using bf16x8 = __attribute__((ext_vector_type(8))) __bf16;
using f32x4  = __attribute__((ext_vector_type(4))) float;
using f4     = __attribute__((ext_vector_type(4))) float;

__device__ __forceinline__ f4 ld4(const float* p) {
  return *reinterpret_cast<const f4*>(p);
}
__device__ __forceinline__ f4 relu4(f4 v) {
  return (f4){fmaxf(v.x, 0.f), fmaxf(v.y, 0.f), fmaxf(v.z, 0.f),
              fmaxf(v.w, 0.f)};
}
__device__ __forceinline__ f4 min4(f4 a, f4 b) {
  return (f4){fminf(a.x, b.x), fminf(a.y, b.y), fminf(a.z, b.z),
              fminf(a.w, b.w)};
}

// elem4<SRC>: elements [r][s..s+3] of the chosen (virtual) tensor.
template <int SRC>
__device__ __forceinline__ f4 elem4(const float* __restrict__ raw,
                                    const float* __restrict__ x,
                                    const float* __restrict__ t1,
                                    const float* __restrict__ p7,
                                    int n, int r, int s) {
  const int nb = n * kMat;
  if constexpr (SRC == SRC_RAW) {
    return ld4(raw + nb + r * kH + s);
  } else if constexpr (SRC == SRC_X) {
    return ld4(x + nb + r * kH + s);
  } else if constexpr (SRC == SRC_T5) {
    return relu4(ld4(x + nb + r * kH + s));
  } else if constexpr (SRC == SRC_T7) {
    return ld4(p7 + r * kH + s) * relu4(ld4(x + nb + r * kH + s));
  } else {
    const int rr = (r + kC - 2) & (kC - 1);      // rolled c-index
    f4 xr = ld4(x + nb + rr * kH + s);
    if constexpr (SRC == SRC_T2) return xr;
    f4 t3 = ld4(t1 + n * kH + s) + xr;
    if constexpr (SRC == SRC_T3) return t3;
    f4 xv = ld4(x + nb + r * kH + s);
    f4 t4 = xv * t3;
    if constexpr (SRC == SRC_T4) return t4;
    return min4(t4, xv);                         // T11
  }
}

// packed f32 pair -> bf16 pair (hw round)
__device__ __forceinline__ unsigned cvtpk(float lo, float hi) {
  unsigned r;
  asm("v_cvt_pk_bf16_f32 %0, %1, %2" : "=v"(r) : "v"(lo), "v"(hi));
  return r;
}

// exact 3-plane split of two f32 values (pair along K)
__device__ __forceinline__ void split2(float a, float b, unsigned& q0,
                                       unsigned& q1, unsigned& q2) {
  q0 = cvtpk(a, b);
  float a0 = __builtin_bit_cast(float, q0 << 16);
  float b0 = __builtin_bit_cast(float, q0 & 0xFFFF0000u);
  float ra = a - a0, rb = b - b0;
  q1 = cvtpk(ra, rb);
  float a1 = __builtin_bit_cast(float, q1 << 16);
  float b1 = __builtin_bit_cast(float, q1 & 0xFFFF0000u);
  q2 = cvtpk(ra - a1, rb - b1);
}

// ---- LDS geometry (ushort units) --------------------------------------
// Plane = 128 rows x 32 ushorts, 2 rows per 128B line. 16B slot
// s = ((r&1)<<2)|(ku>>3) XOR-swizzled with line index -> fragment reads
// land 2-way per bank (free, m136) instead of 8-way. [R6: conflicts == 0]
constexpr int kPlane = 128 * 32;                 // 4096 ushorts = 8 KiB
constexpr int kMatS = 3 * kPlane;                // per-matrix (3 planes)

__device__ __forceinline__ int lds_addr(int r, int ku) {
  int line = r >> 1;
  int slot = ((r & 1) << 2) | (ku >> 3);
  return (line << 6) + ((slot ^ (line & 7)) << 3) + (ku & 7);
}

__device__ __forceinline__ void store3(unsigned short* dst, int r, int ku,
                                       unsigned p0a, unsigned p0b,
                                       unsigned p1a, unsigned p1b,
                                       unsigned p2a, unsigned p2b) {
  int off = lds_addr(r, ku);
  *reinterpret_cast<uint2*>(dst + off)              = make_uint2(p0a, p0b);
  *reinterpret_cast<uint2*>(dst + kPlane + off)     = make_uint2(p1a, p1b);
  *reinterpret_cast<uint2*>(dst + 2 * kPlane + off) = make_uint2(p2a, p2b);
}

// ---- staging: LOAD (global->reg, vectorized) / WRITE (split+ds_write).
// Prefetch tile = struct of four named f4 vectors, by-value only (SROA-safe;
// R5's float[4][4] went to scratch).
struct Tile4 { f4 a, b, c, d; };

template <int SRC, bool TRANS>
__device__ __forceinline__ Tile4 stage_load(const float* __restrict__ raw,
                                            const float* __restrict__ x,
                                            const float* __restrict__ t1,
                                            const float* __restrict__ p7,
                                            int n, int r0, int k0, int tid) {
  Tile4 t;
  if constexpr (!TRANS) {
    t.a = elem4<SRC>(raw, x, t1, p7, n, r0 + (tid >> 3), k0 + ((tid & 7) << 2));
    int e1 = tid + 256;
    t.b = elem4<SRC>(raw, x, t1, p7, n, r0 + (e1 >> 3), k0 + ((e1 & 7) << 2));
    int e2 = tid + 512;
    t.c = elem4<SRC>(raw, x, t1, p7, n, r0 + (e2 >> 3), k0 + ((e2 & 7) << 2));
    int e3 = tid + 768;
    t.d = elem4<SRC>(raw, x, t1, p7, n, r0 + (e3 >> 3), k0 + ((e3 & 7) << 2));
  } else {
    int kb = tid >> 5, mb = tid & 31;
    t.a = elem4<SRC>(raw, x, t1, p7, n, k0 + kb * 4 + 0, r0 + mb * 4);
    t.b = elem4<SRC>(raw, x, t1, p7, n, k0 + kb * 4 + 1, r0 + mb * 4);
    t.c = elem4<SRC>(raw, x, t1, p7, n, k0 + kb * 4 + 2, r0 + mb * 4);
    t.d = elem4<SRC>(raw, x, t1, p7, n, k0 + kb * 4 + 3, r0 + mb * 4);
  }
  return t;
}

template <bool TRANS>
__device__ __forceinline__ void stage_write(unsigned short* dst, Tile4 t,
                                            int tid) {
  if constexpr (!TRANS) {
#define ST_ROW(m, u)                                              \
  {                                                               \
    int e = tid + (u)*256;                                        \
    unsigned p0a, p1a, p2a, p0b, p1b, p2b;                        \
    split2(t.m.x, t.m.y, p0a, p1a, p2a);                          \
    split2(t.m.z, t.m.w, p0b, p1b, p2b);                          \
    store3(dst, e >> 3, (e & 7) << 2, p0a, p0b, p1a, p1b, p2a, p2b); \
  }
    ST_ROW(a, 0) ST_ROW(b, 1) ST_ROW(c, 2) ST_ROW(d, 3)
#undef ST_ROW
  } else {
    int kb = tid >> 5, mb = tid & 31;
#define ST_XP(comp, i)                                            \
  {                                                               \
    unsigned q0a, q1a, q2a, q0b, q1b, q2b;                        \
    split2(t.a.comp, t.b.comp, q0a, q1a, q2a);                    \
    split2(t.c.comp, t.d.comp, q0b, q1b, q2b);                    \
    store3(dst, mb * 4 + (i), kb * 4, q0a, q0b, q1a, q1b, q2a, q2b); \
  }
    ST_XP(x, 0) ST_XP(y, 1) ST_XP(z, 2) ST_XP(w, 3)
#undef ST_XP
  }
}

// C[i,j] = alpha * sum_k opA(i,k)*opB(k,j); 512x512 per batch; bf16x3-split
// MFMA (6 products) f32-accumulate; reg-prefetch of next k-tile.
// waves_per_eu pinned to (3,3): LDS already caps at 3 blocks/CU, and leaving
// the range open made the allocator chase the 6-waves tier by spilling the
// prefetch tiles (R6: VGPR=84, 265 MB/dispatch scratch writes).
template <int ASRC, int AT, int BSRC, int BT>
__global__ __launch_bounds__(256)
__attribute__((amdgpu_waves_per_eu(3, 3))) void gemm_kernel(
    const float* __restrict__ Araw, const float* __restrict__ Braw,
    const float* __restrict__ x, const float* __restrict__ t1,
    const float* __restrict__ p7, float* __restrict__ C, float alpha) {
  __shared__ unsigned short smem[2 * kMatS];     // 49152 B -> 3 blocks/CU
  const int n = blockIdx.z;
  const int i0 = blockIdx.y * 128;
  const int j0 = blockIdx.x * 128;
  const int tid = threadIdx.x;
  const int lane = tid & 63;
  const int wid = tid >> 6;
  const int wr = wid >> 1, wc = wid & 1;         // wave -> 64x64 sub-tile

  f32x4 acc[4][4];
#pragma unroll
  for (int a = 0; a < 4; ++a)
#pragma unroll
    for (int b = 0; b < 4; ++b) acc[a][b] = (f32x4)0.f;

  const int frow = lane & 15;                    // fragment row/col within 16
  const int kq = (lane >> 4) * 8;                // k-offset (ushort units)

  Tile4 vA = stage_load<ASRC, AT == 1>(Araw, x, t1, p7, n, i0, 0, tid);
  Tile4 vB = stage_load<BSRC, BT == 0>(Braw, x, t1, p7, n, j0, 0, tid);

  for (int k0 = 0; k0 < kC; k0 += 32) {
    stage_write<AT == 1>(smem, vA, tid);
    stage_write<BT == 0>(smem + kMatS, vB, tid);
    if (k0 + 32 < kC) {                          // issue next-tile loads before
      vA = stage_load<ASRC, AT == 1>(Araw, x, t1, p7, n, i0, k0 + 32, tid);
      vB = stage_load<BSRC, BT == 0>(Braw, x, t1, p7, n, j0, k0 + 32, tid);
    }                                            // the barrier; complete under MFMA
    __syncthreads();

    bf16x8 B0[4], B1[4], B2[4];
#pragma unroll
    for (int nj = 0; nj < 4; ++nj) {
      int off = kMatS + lds_addr(wc * 64 + nj * 16 + frow, kq);
      B0[nj] = *reinterpret_cast<const bf16x8*>(smem + off);
      B1[nj] = *reinterpret_cast<const bf16x8*>(smem + kPlane + off);
      B2[nj] = *reinterpret_cast<const bf16x8*>(smem + 2 * kPlane + off);
    }
#pragma unroll
    for (int mi = 0; mi < 4; ++mi) {
      int off = lds_addr(wr * 64 + mi * 16 + frow, kq);
      bf16x8 A0 = *reinterpret_cast<const bf16x8*>(smem + off);
      bf16x8 A1 = *reinterpret_cast<const bf16x8*>(smem + kPlane + off);
      bf16x8 A2 = *reinterpret_cast<const bf16x8*>(smem + 2 * kPlane + off);
#pragma unroll
      for (int nj = 0; nj < 4; ++nj) {
        f32x4 c = acc[mi][nj];
        c = __builtin_amdgcn_mfma_f32_16x16x32_bf16(A1, B1[nj], c, 0, 0, 0);
        c = __builtin_amdgcn_mfma_f32_16x16x32_bf16(A0, B2[nj], c, 0, 0, 0);
        c = __builtin_amdgcn_mfma_f32_16x16x32_bf16(A2, B0[nj], c, 0, 0, 0);
        c = __builtin_amdgcn_mfma_f32_16x16x32_bf16(A0, B1[nj], c, 0, 0, 0);
        c = __builtin_amdgcn_mfma_f32_16x16x32_bf16(A1, B0[nj], c, 0, 0, 0);
        c = __builtin_amdgcn_mfma_f32_16x16x32_bf16(A0, B0[nj], c, 0, 0, 0);
        acc[mi][nj] = c;
      }
    }
    __syncthreads();
  }

  // epilogue: C/D layout col=lane&15, row=(lane>>4)*4+reg (m89-verified)
  const int nb = n * kMat;
  const int rbase = (lane >> 4) * 4;
#pragma unroll
  for (int mi = 0; mi < 4; ++mi) {
#pragma unroll
    for (int nj = 0; nj < 4; ++nj) {
      int row0 = i0 + wr * 64 + mi * 16 + rbase;
      int col = j0 + wc * 64 + nj * 16 + frow;
      float* cp = C + nb + row0 * kH + col;
#pragma unroll
      for (int r = 0; r < 4; ++r) cp[r * kH] = acc[mi][nj][r] * alpha;
    }
  }
}

// t1[n,h] = sum_c x[n,c,h] * w[c]
__global__ __launch_bounds__(256) void t1_kernel(const float* __restrict__ x,
                                                 const float* __restrict__ w,
                                                 float* __restrict__ t1) {
  int idx = blockIdx.x * 256 + threadIdx.x;      // n*kH + h
  int n = idx >> 9;
  const float* xp = x + n * kMat + (idx & (kH - 1));
  float s = 0.f;
#pragma unroll 8
  for (int c = 0; c < kC; ++c) s = fmaf(xp[c * kH], w[c], s);
  t1[idx] = s;
}

// in-place stable softmax over rows of 512 floats; one block per row
__global__ __launch_bounds__(256) void softmax_kernel(float* __restrict__ buf) {
  __shared__ float red[8];
  float* p = buf + (size_t)blockIdx.x * kH;
  int t = threadIdx.x;
  float2 v = reinterpret_cast<float2*>(p)[t];
  float m = fmaxf(v.x, v.y);
#pragma unroll
  for (int o = 32; o; o >>= 1) m = fmaxf(m, __shfl_xor(m, o));
  if ((t & 63) == 0) red[t >> 6] = m;
  __syncthreads();
  m = fmaxf(fmaxf(red[0], red[1]), fmaxf(red[2], red[3]));
  float e0 = expf(v.x - m), e1 = expf(v.y - m);
  float s = e0 + e1;
#pragma unroll
  for (int o = 32; o; o >>= 1) s += __shfl_xor(s, o);
  __syncthreads();
  if ((t & 63) == 0) red[4 + (t >> 6)] = s;
  __syncthreads();
  s = red[4] + red[5] + red[6] + red[7];
  float inv = 1.f / s;
  reinterpret_cast<float2*>(p)[t] = make_float2(e0 * inv, e1 * inv);
}

}  // namespace

extern "C" void kernel_launch(void* const* d_in, const int* in_sizes, int n_in,
                              void* d_out, int out_size, void* d_ws,
                              size_t ws_size, hipStream_t stream) {
  (void)in_sizes; (void)n_in; (void)out_size;
  const float* x  = (const float*)d_in[0];
  const float* w  = (const float*)d_in[1];   // p1_w (C,1)
  const float* p7 = (const float*)d_in[2];   // p7_w (1,C,H)
  float* out = (float*)d_out;

  const size_t BUF = (size_t)kN * kMat;
  const size_t need = (4 * BUF + (size_t)kN * kH) * sizeof(float);
  float* ws = (float*)d_ws;
  if (ws_size < need) {
    static float* g_extra = nullptr;           // first (uncaptured) call only
    if (!g_extra) (void)hipMalloc((void**)&g_extra, need);
    ws = g_extra;
  }
  float* b0 = ws;
  float* b1 = b0 + BUF;
  float* b2 = b1 + BUF;
  float* b3 = b2 + BUF;
  float* t1 = b3 + BUF;

  dim3 gg(4, 4, kN);
  dim3 bb(256);
  const int rows = kN * kH;                    // 32768

  t1_kernel<<<rows / 256, bb, 0, stream>>>(x, w, t1);

  // t9 = t5 @ t4^T * invS                                  -> b0
  gemm_kernel<SRC_T5, 0, SRC_T4, 1><<<gg, bb, 0, stream>>>(nullptr, nullptr, x, t1, p7, b0, kInvS);
  // t10 = softmax(t7 @ t3^T * invS)                        -> b1
  gemm_kernel<SRC_T7, 0, SRC_T3, 1><<<gg, bb, 0, stream>>>(nullptr, nullptr, x, t1, p7, b1, kInvS);
  softmax_kernel<<<rows, bb, 0, stream>>>(b1);
  // t14 = softmax(S14), S14[i,j] = sum_k t9[k,i]*t10[j,k]  -> b2
  gemm_kernel<SRC_RAW, 1, SRC_RAW, 1><<<gg, bb, 0, stream>>>(b0, b1, x, t1, p7, b2, kInvS);
  softmax_kernel<<<rows, bb, 0, stream>>>(b2);
  // t12[i,h] = sum_d t9[d,i]*t7[d,h] * invS                -> b1 (t10 dead)
  gemm_kernel<SRC_RAW, 1, SRC_T7, 0><<<gg, bb, 0, stream>>>(b0, nullptr, x, t1, p7, b1, kInvS);
  // t16[h,j] = sum_k t12[k,h]*t14[j,k] * invS              -> b0 (t9 dead)
  gemm_kernel<SRC_RAW, 1, SRC_RAW, 1><<<gg, bb, 0, stream>>>(b1, b2, x, t1, p7, b0, kInvS);
  // t13[h,g] = sum_c t11[c,h]*t2[c,g] * invS               -> b1 (t12 dead)
  gemm_kernel<SRC_T11, 1, SRC_T2, 0><<<gg, bb, 0, stream>>>(nullptr, nullptr, x, t1, p7, b1, kInvS);
  // t8 = softmax(t5^T @ x * invS)                          -> b2 (t14 dead)
  gemm_kernel<SRC_T5, 1, SRC_X, 0><<<gg, bb, 0, stream>>>(nullptr, nullptr, x, t1, p7, b2, kInvS);
  softmax_kernel<<<rows, bb, 0, stream>>>(b2);
  // t15 = softmax(t13 @ t8 * invS)                         -> b3
  gemm_kernel<SRC_RAW, 0, SRC_RAW, 0><<<gg, bb, 0, stream>>>(b1, b2, x, t1, p7, b3, kInvS);
  softmax_kernel<<<rows, bb, 0, stream>>>(b3);
  // t17[c,j] = sum_k t16[k,c]*t15[k,j] * invS              -> out
  gemm_kernel<SRC_RAW, 1, SRC_RAW, 0><<<gg, bb, 0, stream>>>(b0, b3, x, t1, p7, out, kInvS);
}

// Round 9
// 1345.385 us; speedup vs baseline: 2.0350x; 1.0154x over previous
//
#include <hip/hip_runtime.h>
#include <math.h>

namespace {

constexpr int kC = 512;
constexpr int kH = 512;
constexpr int kN = 64;
constexpr int kMat = kC * kH;                    // 262144
constexpr float kInvS = 0.04419417382415922f;    // 1/sqrt(512)

enum { SRC_RAW = 0, SRC_X, SRC_T2, SRC_T3, SRC_T4, SRC_T5, SRC_T7, SRC_T11 };

using bf16x8 = __attribute__((ext_vector_type(8))) __bf16;
using f32x4  = __attribute__((ext_vector_type(4))) float;
using f4     = __attribute__((ext_vector_type(4))) float;

__device__ __forceinline__ f4 ld4(const float* p) {
  return *reinterpret_cast<const f4*>(p);
}
__device__ __forceinline__ f4 relu4(f4 v) {
  return (f4){fmaxf(v.x, 0.f), fmaxf(v.y, 0.f), fmaxf(v.z, 0.f),
              fmaxf(v.w, 0.f)};
}
__device__ __forceinline__ f4 min4(f4 a, f4 b) {
  return (f4){fminf(a.x, b.x), fminf(a.y, b.y), fminf(a.z, b.z),
              fminf(a.w, b.w)};
}

// elem4<SRC>: elements [r][s..s+3] of the chosen (virtual) tensor.
template <int SRC>
__device__ __forceinline__ f4 elem4(const float* __restrict__ raw,
                                    const float* __restrict__ x,
                                    const float* __restrict__ t1,
                                    const float* __restrict__ p7,
                                    int n, int r, int s) {
  const int nb = n * kMat;
  if constexpr (SRC == SRC_RAW) {
    return ld4(raw + nb + r * kH + s);
  } else if constexpr (SRC == SRC_X) {
    return ld4(x + nb + r * kH + s);
  } else if constexpr (SRC == SRC_T5) {
    return relu4(ld4(x + nb + r * kH + s));
  } else if constexpr (SRC == SRC_T7) {
    return ld4(p7 + r * kH + s) * relu4(ld4(x + nb + r * kH + s));
  } else {
    const int rr = (r + kC - 2) & (kC - 1);      // rolled c-index
    f4 xr = ld4(x + nb + rr * kH + s);
    if constexpr (SRC == SRC_T2) return xr;
    f4 t3 = ld4(t1 + n * kH + s) + xr;
    if constexpr (SRC == SRC_T3) return t3;
    f4 xv = ld4(x + nb + r * kH + s);
    f4 t4 = xv * t3;
    if constexpr (SRC == SRC_T4) return t4;
    return min4(t4, xv);                         // T11
  }
}

// packed f32 pair -> bf16 pair (hw round)
__device__ __forceinline__ unsigned cvtpk(float lo, float hi) {
  unsigned r;
  asm("v_cvt_pk_bf16_f32 %0, %1, %2" : "=v"(r) : "v"(lo), "v"(hi));
  return r;
}

// exact 3-plane split of two f32 values (pair along K)
__device__ __forceinline__ void split2(float a, float b, unsigned& q0,
                                       unsigned& q1, unsigned& q2) {
  q0 = cvtpk(a, b);
  float a0 = __builtin_bit_cast(float, q0 << 16);
  float b0 = __builtin_bit_cast(float, q0 & 0xFFFF0000u);
  float ra = a - a0, rb = b - b0;
  q1 = cvtpk(ra, rb);
  float a1 = __builtin_bit_cast(float, q1 << 16);
  float b1 = __builtin_bit_cast(float, q1 & 0xFFFF0000u);
  q2 = cvtpk(ra - a1, rb - b1);
}

// ---- LDS geometry (ushort units) --------------------------------------
// Plane = 128 rows x 32 ushorts, 2 rows per 128B line. 16B slot
// s = ((r&1)<<2)|(ku>>3) XOR-swizzled with line index. Verified on HW:
// SQ_LDS_BANK_CONFLICT == 0 for both read and write patterns (R6/R7).
constexpr int kPlane = 128 * 32;                 // 4096 ushorts = 8 KiB
constexpr int kMatS = 3 * kPlane;                // per-matrix (3 planes)

__device__ __forceinline__ int lds_addr(int r, int ku) {
  int line = r >> 1;
  int slot = ((r & 1) << 2) | (ku >> 3);
  return (line << 6) + ((slot ^ (line & 7)) << 3) + (ku & 7);
}

__device__ __forceinline__ void store3(unsigned short* dst, int r, int ku,
                                       unsigned p0a, unsigned p0b,
                                       unsigned p1a, unsigned p1b,
                                       unsigned p2a, unsigned p2b) {
  int off = lds_addr(r, ku);
  *reinterpret_cast<uint2*>(dst + off)              = make_uint2(p0a, p0b);
  *reinterpret_cast<uint2*>(dst + kPlane + off)     = make_uint2(p1a, p1b);
  *reinterpret_cast<uint2*>(dst + 2 * kPlane + off) = make_uint2(p2a, p2b);
}

// ---- staging: LOAD (global->reg, vectorized) / WRITE (split+ds_write).
// Tile = struct of four named f4 vectors, by-value only (SROA-safe).
// NOTE (R5-R7 lesson): these tiles must NOT live across the MFMA section —
// at 3 waves/SIMD the budget is 168 VGPRs and acc(64)+frags(60)+tiles(32)
// exceeds it, forcing a scratch spill (330 MB/dispatch). Load and write
// back-to-back inside the staging phase only.
struct Tile4 { f4 a, b, c, d; };

template <int SRC, bool TRANS>
__device__ __forceinline__ Tile4 stage_load(const float* __restrict__ raw,
                                            const float* __restrict__ x,
                                            const float* __restrict__ t1,
                                            const float* __restrict__ p7,
                                            int n, int r0, int k0, int tid) {
  Tile4 t;
  if constexpr (!TRANS) {
    t.a = elem4<SRC>(raw, x, t1, p7, n, r0 + (tid >> 3), k0 + ((tid & 7) << 2));
    int e1 = tid + 256;
    t.b = elem4<SRC>(raw, x, t1, p7, n, r0 + (e1 >> 3), k0 + ((e1 & 7) << 2));
    int e2 = tid + 512;
    t.c = elem4<SRC>(raw, x, t1, p7, n, r0 + (e2 >> 3), k0 + ((e2 & 7) << 2));
    int e3 = tid + 768;
    t.d = elem4<SRC>(raw, x, t1, p7, n, r0 + (e3 >> 3), k0 + ((e3 & 7) << 2));
  } else {
    int kb = tid >> 5, mb = tid & 31;
    t.a = elem4<SRC>(raw, x, t1, p7, n, k0 + kb * 4 + 0, r0 + mb * 4);
    t.b = elem4<SRC>(raw, x, t1, p7, n, k0 + kb * 4 + 1, r0 + mb * 4);
    t.c = elem4<SRC>(raw, x, t1, p7, n, k0 + kb * 4 + 2, r0 + mb * 4);
    t.d = elem4<SRC>(raw, x, t1, p7, n, k0 + kb * 4 + 3, r0 + mb * 4);
  }
  return t;
}

template <bool TRANS>
__device__ __forceinline__ void stage_write(unsigned short* dst, Tile4 t,
                                            int tid) {
  if constexpr (!TRANS) {
#define ST_ROW(m, u)                                              \
  {                                                               \
    int e = tid + (u)*256;                                        \
    unsigned p0a, p1a, p2a, p0b, p1b, p2b;                        \
    split2(t.m.x, t.m.y, p0a, p1a, p2a);                          \
    split2(t.m.z, t.m.w, p0b, p1b, p2b);                          \
    store3(dst, e >> 3, (e & 7) << 2, p0a, p0b, p1a, p1b, p2a, p2b); \
  }
    ST_ROW(a, 0) ST_ROW(b, 1) ST_ROW(c, 2) ST_ROW(d, 3)
#undef ST_ROW
  } else {
    int kb = tid >> 5, mb = tid & 31;
#define ST_XP(comp, i)                                            \
  {                                                               \
    unsigned q0a, q1a, q2a, q0b, q1b, q2b;                        \
    split2(t.a.comp, t.b.comp, q0a, q1a, q2a);                    \
    split2(t.c.comp, t.d.comp, q0b, q1b, q2b);                    \
    store3(dst, mb * 4 + (i), kb * 4, q0a, q0b, q1a, q1b, q2a, q2b); \
  }
    ST_XP(x, 0) ST_XP(y, 1) ST_XP(z, 2) ST_XP(w, 3)
#undef ST_XP
  }
}

// C[i,j] = alpha * sum_k opA(i,k)*opB(k,j); 512x512 per batch; bf16x3-split
// MFMA (6 products) with f32 accumulate. Clean 2-phase k-loop: stage ->
// barrier -> MFMA -> barrier. Cross-phase overlap comes from 3 resident
// blocks/CU (m114 wave-level MFMA/VALU co-issue), not register prefetch.
template <int ASRC, int AT, int BSRC, int BT>
__global__ __launch_bounds__(256, 2) void gemm_kernel(
    const float* __restrict__ Araw, const float* __restrict__ Braw,
    const float* __restrict__ x, const float* __restrict__ t1,
    const float* __restrict__ p7, float* __restrict__ C, float alpha) {
  __shared__ unsigned short smem[2 * kMatS];     // 49152 B -> 3 blocks/CU
  const int n = blockIdx.z;
  const int i0 = blockIdx.y * 128;
  const int j0 = blockIdx.x * 128;
  const int tid = threadIdx.x;
  const int lane = tid & 63;
  const int wid = tid >> 6;
  const int wr = wid >> 1, wc = wid & 1;         // wave -> 64x64 sub-tile

  f32x4 acc[4][4];
#pragma unroll
  for (int a = 0; a < 4; ++a)
#pragma unroll
    for (int b = 0; b < 4; ++b) acc[a][b] = (f32x4)0.f;

  const int frow = lane & 15;                    // fragment row/col within 16
  const int kq = (lane >> 4) * 8;                // k-offset (ushort units)

  for (int k0 = 0; k0 < kC; k0 += 32) {
    // all 8 global loads issue before any split/ds_write (latency overlap)
    Tile4 vA = stage_load<ASRC, AT == 1>(Araw, x, t1, p7, n, i0, k0, tid);
    Tile4 vB = stage_load<BSRC, BT == 0>(Braw, x, t1, p7, n, j0, k0, tid);
    stage_write<AT == 1>(smem, vA, tid);
    stage_write<BT == 0>(smem + kMatS, vB, tid);
    __syncthreads();

    bf16x8 B0[4], B1[4], B2[4];
#pragma unroll
    for (int nj = 0; nj < 4; ++nj) {
      int off = kMatS + lds_addr(wc * 64 + nj * 16 + frow, kq);
      B0[nj] = *reinterpret_cast<const bf16x8*>(smem + off);
      B1[nj] = *reinterpret_cast<const bf16x8*>(smem + kPlane + off);
      B2[nj] = *reinterpret_cast<const bf16x8*>(smem + 2 * kPlane + off);
    }
#pragma unroll
    for (int mi = 0; mi < 4; ++mi) {
      int off = lds_addr(wr * 64 + mi * 16 + frow, kq);
      bf16x8 A0 = *reinterpret_cast<const bf16x8*>(smem + off);
      bf16x8 A1 = *reinterpret_cast<const bf16x8*>(smem + kPlane + off);
      bf16x8 A2 = *reinterpret_cast<const bf16x8*>(smem + 2 * kPlane + off);
#pragma unroll
      for (int nj = 0; nj < 4; ++nj) {
        f32x4 c = acc[mi][nj];
        c = __builtin_amdgcn_mfma_f32_16x16x32_bf16(A1, B1[nj], c, 0, 0, 0);
        c = __builtin_amdgcn_mfma_f32_16x16x32_bf16(A0, B2[nj], c, 0, 0, 0);
        c = __builtin_amdgcn_mfma_f32_16x16x32_bf16(A2, B0[nj], c, 0, 0, 0);
        c = __builtin_amdgcn_mfma_f32_16x16x32_bf16(A0, B1[nj], c, 0, 0, 0);
        c = __builtin_amdgcn_mfma_f32_16x16x32_bf16(A1, B0[nj], c, 0, 0, 0);
        c = __builtin_amdgcn_mfma_f32_16x16x32_bf16(A0, B0[nj], c, 0, 0, 0);
        acc[mi][nj] = c;
      }
    }
    __syncthreads();
  }

  // epilogue: C/D layout col=lane&15, row=(lane>>4)*4+reg (m89-verified)
  const int nb = n * kMat;
  const int rbase = (lane >> 4) * 4;
#pragma unroll
  for (int mi = 0; mi < 4; ++mi) {
#pragma unroll
    for (int nj = 0; nj < 4; ++nj) {
      int row0 = i0 + wr * 64 + mi * 16 + rbase;
      int col = j0 + wc * 64 + nj * 16 + frow;
      float* cp = C + nb + row0 * kH + col;
#pragma unroll
      for (int r = 0; r < 4; ++r) cp[r * kH] = acc[mi][nj][r] * alpha;
    }
  }
}

// t1[n,h] = sum_c x[n,c,h] * w[c]
__global__ __launch_bounds__(256) void t1_kernel(const float* __restrict__ x,
                                                 const float* __restrict__ w,
                                                 float* __restrict__ t1) {
  int idx = blockIdx.x * 256 + threadIdx.x;      // n*kH + h
  int n = idx >> 9;
  const float* xp = x + n * kMat + (idx & (kH - 1));
  float s = 0.f;
#pragma unroll 8
  for (int c = 0; c < kC; ++c) s = fmaf(xp[c * kH], w[c], s);
  t1[idx] = s;
}

// in-place stable softmax over rows of 512 floats; one block per row
__global__ __launch_bounds__(256) void softmax_kernel(float* __restrict__ buf) {
  __shared__ float red[8];
  float* p = buf + (size_t)blockIdx.x * kH;
  int t = threadIdx.x;
  float2 v = reinterpret_cast<float2*>(p)[t];
  float m = fmaxf(v.x, v.y);
#pragma unroll
  for (int o = 32; o; o >>= 1) m = fmaxf(m, __shfl_xor(m, o));
  if ((t & 63) == 0) red[t >> 6] = m;
  __syncthreads();
  m = fmaxf(fmaxf(red[0], red[1]), fmaxf(red[2], red[3]));
  float e0 = expf(v.x - m), e1 = expf(v.y - m);
  float s = e0 + e1;
#pragma unroll
  for (int o = 32; o; o >>= 1) s += __shfl_xor(s, o);
  __syncthreads();
  if ((t & 63) == 0) red[4 + (t >> 6)] = s;
  __syncthreads();
  s = red[4] + red[5] + red[6] + red[7];
  float inv = 1.f / s;
  reinterpret_cast<float2*>(p)[t] = make_float2(e0 * inv, e1 * inv);
}

}  // namespace

extern "C" void kernel_launch(void* const* d_in, const int* in_sizes, int n_in,
                              void* d_out, int out_size, void* d_ws,
                              size_t ws_size, hipStream_t stream) {
  (void)in_sizes; (void)n_in; (void)out_size;
  const float* x  = (const float*)d_in[0];
  const float* w  = (const float*)d_in[1];   // p1_w (C,1)
  const float* p7 = (const float*)d_in[2];   // p7_w (1,C,H)
  float* out = (float*)d_out;

  const size_t BUF = (size_t)kN * kMat;
  const size_t need = (4 * BUF + (size_t)kN * kH) * sizeof(float);
  float* ws = (float*)d_ws;
  if (ws_size < need) {
    static float* g_extra = nullptr;           // first (uncaptured) call only
    if (!g_extra) (void)hipMalloc((void**)&g_extra, need);
    ws = g_extra;
  }
  float* b0 = ws;
  float* b1 = b0 + BUF;
  float* b2 = b1 + BUF;
  float* b3 = b2 + BUF;
  float* t1 = b3 + BUF;

  dim3 gg(4, 4, kN);
  dim3 bb(256);
  const int rows = kN * kH;                    // 32768

  t1_kernel<<<rows / 256, bb, 0, stream>>>(x, w, t1);

  // t9 = t5 @ t4^T * invS                                  -> b0
  gemm_kernel<SRC_T5, 0, SRC_T4, 1><<<gg, bb, 0, stream>>>(nullptr, nullptr, x, t1, p7, b0, kInvS);
  // t10 = softmax(t7 @ t3^T * invS)                        -> b1
  gemm_kernel<SRC_T7, 0, SRC_T3, 1><<<gg, bb, 0, stream>>>(nullptr, nullptr, x, t1, p7, b1, kInvS);
  softmax_kernel<<<rows, bb, 0, stream>>>(b1);
  // t14 = softmax(S14), S14[i,j] = sum_k t9[k,i]*t10[j,k]  -> b2
  gemm_kernel<SRC_RAW, 1, SRC_RAW, 1><<<gg, bb, 0, stream>>>(b0, b1, x, t1, p7, b2, kInvS);
  softmax_kernel<<<rows, bb, 0, stream>>>(b2);
  // t12[i,h] = sum_d t9[d,i]*t7[d,h] * invS                -> b1 (t10 dead)
  gemm_kernel<SRC_RAW, 1, SRC_T7, 0><<<gg, bb, 0, stream>>>(b0, nullptr, x, t1, p7, b1, kInvS);
  // t16[h,j] = sum_k t12[k,h]*t14[j,k] * invS              -> b0 (t9 dead)
  gemm_kernel<SRC_RAW, 1, SRC_RAW, 1><<<gg, bb, 0, stream>>>(b1, b2, x, t1, p7, b0, kInvS);
  // t13[h,g] = sum_c t11[c,h]*t2[c,g] * invS               -> b1 (t12 dead)
  gemm_kernel<SRC_T11, 1, SRC_T2, 0><<<gg, bb, 0, stream>>>(nullptr, nullptr, x, t1, p7, b1, kInvS);
  // t8 = softmax(t5^T @ x * invS)                          -> b2 (t14 dead)
  gemm_kernel<SRC_T5, 1, SRC_X, 0><<<gg, bb, 0, stream>>>(nullptr, nullptr, x, t1, p7, b2, kInvS);
  softmax_kernel<<<rows, bb, 0, stream>>>(b2);
  // t15 = softmax(t13 @ t8 * invS)                         -> b3
  gemm_kernel<SRC_RAW, 0, SRC_RAW, 0><<<gg, bb, 0, stream>>>(b1, b2, x, t1, p7, b3, kInvS);
  softmax_kernel<<<rows, bb, 0, stream>>>(b3);
  // t17[c,j] = sum_k t16[k,c]*t15[k,j] * invS              -> out
  gemm_kernel<SRC_RAW, 1, SRC_RAW, 0><<<gg, bb, 0, stream>>>(b0, b3, x, t1, p7, out, kInvS);
}